// Round 2
// baseline (668.984 us; speedup 1.0000x reference)
//
#include <hip/hip_runtime.h>
#include <stdint.h>

typedef short bf16x8 __attribute__((ext_vector_type(8)));
typedef float f32x4 __attribute__((ext_vector_type(4)));
typedef unsigned short u16x8 __attribute__((ext_vector_type(8)));

__device__ __forceinline__ unsigned short f2bf(float f){
  uint32_t u = __builtin_bit_cast(uint32_t, f);
  u += 0x7FFFu + ((u >> 16) & 1u);
  return (unsigned short)(u >> 16);
}
__device__ __forceinline__ float bf2f(unsigned short h){
  uint32_t u = ((uint32_t)h) << 16;
  return __builtin_bit_cast(float, u);
}

__device__ __forceinline__ void gload_lds16(const void* g, void* l){
  __builtin_amdgcn_global_load_lds(
      (const __attribute__((address_space(1))) uint32_t*)(g),
      (__attribute__((address_space(3))) uint32_t*)(l),
      16, 0, 0);
}

// ---------------- convert x (fp32 -> bf16), 8 elems/thread ----------------
__global__ __launch_bounds__(256) void convert_x_k(const float* __restrict__ x,
                                                   unsigned short* __restrict__ xb){
  size_t i = (size_t)blockIdx.x * 256 + threadIdx.x;
  const float4* p = (const float4*)x + i * 2;
  float4 a = p[0], b = p[1];
  u16x8 o;
  o[0] = f2bf(a.x); o[1] = f2bf(a.y); o[2] = f2bf(a.z); o[3] = f2bf(a.w);
  o[4] = f2bf(b.x); o[5] = f2bf(b.y); o[6] = f2bf(b.z); o[7] = f2bf(b.w);
  *(u16x8*)(xb + i * 8) = o;
}

// ---------------- transpose + convert weights -----------------------------
__global__ __launch_bounds__(256) void transpose_w_k(const float* __restrict__ Wqkv,
                                                     const float* __restrict__ Wproj,
                                                     unsigned short* __restrict__ Wqkvt,
                                                     unsigned short* __restrict__ Wprojt){
  int i = blockIdx.x * 256 + threadIdx.x;
  if (i < 786432){
    int j = i >> 9, c = i & 511;
    Wqkvt[i] = f2bf(Wqkv[(size_t)c * 1536 + j]);
  } else {
    int e = i - 786432;
    int j = e >> 9, c = e & 511;
    Wprojt[e] = f2bf(Wproj[(size_t)c * 512 + j]);
  }
}

// ---------------- GEMM: C = A(Mx512) * Bt(Nx512)^T, bf16 MFMA --------------
// EPI 0: qkv epilogue (bias, relu/pos_enc, split into per-head q/k/v bf16)
// EPI 1: proj epilogue (bias, fp32 out)
template<int EPI>
__global__ __launch_bounds__(256, 2) void gemm_k(
    const unsigned short* __restrict__ A,
    const unsigned short* __restrict__ Bt,
    const float* __restrict__ bias,
    const float* __restrict__ pos_enc,
    unsigned short* __restrict__ oq,
    unsigned short* __restrict__ ok,
    unsigned short* __restrict__ ov,
    float* __restrict__ op,
    int NTN)
{
  __shared__ unsigned short As[128 * 64];
  __shared__ unsigned short Bs[128 * 64];
  int tid = threadIdx.x, lane = tid & 63, wid = tid >> 6;
  int nwg = gridDim.x;
  int b0 = blockIdx.x;
  int cpx = nwg >> 3;
  int swz = (b0 & 7) * cpx + (b0 >> 3);      // XCD-aware swizzle (nwg % 8 == 0)
  int tm = swz / NTN, tn = swz - tm * NTN;
  int row0 = tm << 7, col0 = tn << 7;
  int wr = wid >> 1, wc = wid & 1;

  f32x4 acc[4][4];
  #pragma unroll
  for (int m = 0; m < 4; ++m)
    #pragma unroll
    for (int n = 0; n < 4; ++n)
      acc[m][n] = (f32x4){0.f, 0.f, 0.f, 0.f};

  int sr = lane >> 3;            // row within 8-row chunk
  int sc = (lane & 7) * 8;       // k column (8 bf16 = 16B)

  for (int kt = 0; kt < 8; ++kt){
    int k0 = kt * 64;
    #pragma unroll
    for (int it = 0; it < 4; ++it){
      int chunk = wid * 4 + it;
      int r = chunk * 8 + sr;
      gload_lds16(A  + (size_t)(row0 + r) * 512 + k0 + sc, &As[chunk * 512]);
      gload_lds16(Bt + (size_t)(col0 + r) * 512 + k0 + sc, &Bs[chunk * 512]);
    }
    __syncthreads();
    #pragma unroll
    for (int kk = 0; kk < 2; ++kk){
      bf16x8 af[4], bfr[4];
      int kidx = kk * 32 + (lane >> 4) * 8;
      #pragma unroll
      for (int m = 0; m < 4; ++m)
        af[m] = *(const bf16x8*)&As[(wr * 64 + m * 16 + (lane & 15)) * 64 + kidx];
      #pragma unroll
      for (int n = 0; n < 4; ++n)
        bfr[n] = *(const bf16x8*)&Bs[(wc * 64 + n * 16 + (lane & 15)) * 64 + kidx];
      #pragma unroll
      for (int m = 0; m < 4; ++m)
        #pragma unroll
        for (int n = 0; n < 4; ++n)
          acc[m][n] = __builtin_amdgcn_mfma_f32_16x16x32_bf16(af[m], bfr[n], acc[m][n], 0, 0, 0);
    }
    __syncthreads();
  }

  #pragma unroll
  for (int m = 0; m < 4; ++m){
    #pragma unroll
    for (int n = 0; n < 4; ++n){
      #pragma unroll
      for (int r = 0; r < 4; ++r){
        int rrow = row0 + wr * 64 + m * 16 + (lane >> 4) * 4 + r;
        int ccol = col0 + wc * 64 + n * 16 + (lane & 15);
        float val = acc[m][n][r] + bias[ccol];
        if constexpr (EPI == 0){
          int part = ccol >> 9;
          int cc = ccol & 511;
          int bb = rrow >> 12, nn = rrow & 4095;
          int h = cc >> 5, d = cc & 31;
          size_t dst = ((size_t)((bb << 4) + h) * 4096 + nn) * 32 + d;
          if (part == 0){
            oq[dst] = f2bf(fmaxf(val, 0.f));
          } else if (part == 1){
            val += pos_enc[(size_t)nn * 512 + cc];
            ok[dst] = f2bf(fmaxf(val, 0.f));
          } else {
            ov[dst] = f2bf(val);
          }
        } else {
          op[(size_t)rrow * 512 + ccol] = val;
        }
      }
    }
  }
}

// ---------------- kv = k^T v (32x32) + ksum, per head, 4-way n-split ------
__global__ __launch_bounds__(256) void kv_k(const unsigned short* __restrict__ kbuf,
                                            const unsigned short* __restrict__ vbuf,
                                            float* __restrict__ kvb,
                                            float* __restrict__ ksb){
  int bh  = blockIdx.x >> 2;
  int seg = blockIdx.x & 3;
  __shared__ float ks[64][36];
  __shared__ float vs[64][36];
  __shared__ float red[4][64][16];
  __shared__ float ksred[4][8][4];
  int tid = threadIdx.x;
  int g = tid >> 6, gi = tid & 63;
  int c0 = (gi >> 3) * 4, d0 = (gi & 7) * 4;
  float acc[4][4] = {};
  float ksacc[4] = {0.f, 0.f, 0.f, 0.f};
  const unsigned short* kb = kbuf + (size_t)bh * 4096 * 32 + (size_t)seg * 1024 * 32;
  const unsigned short* vb = vbuf + (size_t)bh * 4096 * 32 + (size_t)seg * 1024 * 32;
  int er = tid >> 2;
  int ec = (tid & 3) * 8;
  for (int t = 0; t < 16; ++t){
    __syncthreads();
    u16x8 kk8 = *(const u16x8*)(kb + ((size_t)t * 64 + er) * 32 + ec);
    u16x8 vv8 = *(const u16x8*)(vb + ((size_t)t * 64 + er) * 32 + ec);
    #pragma unroll
    for (int i = 0; i < 8; ++i){ ks[er][ec + i] = bf2f(kk8[i]); vs[er][ec + i] = bf2f(vv8[i]); }
    __syncthreads();
    for (int nn = g; nn < 64; nn += 4){
      f32x4 k4 = *(const f32x4*)&ks[nn][c0];
      f32x4 v4 = *(const f32x4*)&vs[nn][d0];
      #pragma unroll
      for (int i = 0; i < 4; ++i)
        #pragma unroll
        for (int j = 0; j < 4; ++j)
          acc[i][j] += k4[i] * v4[j];
      if ((gi & 7) == 0){
        #pragma unroll
        for (int i = 0; i < 4; ++i) ksacc[i] += k4[i];
      }
    }
  }
  __syncthreads();
  #pragma unroll
  for (int i = 0; i < 4; ++i)
    #pragma unroll
    for (int j = 0; j < 4; ++j)
      red[g][gi][i * 4 + j] = acc[i][j];
  if ((gi & 7) == 0){
    #pragma unroll
    for (int i = 0; i < 4; ++i) ksred[g][gi >> 3][i] = ksacc[i];
  }
  __syncthreads();
  for (int s = tid; s < 1024; s += 256){
    int gi2 = s >> 4, e = s & 15;
    float sum = red[0][gi2][e] + red[1][gi2][e] + red[2][gi2][e] + red[3][gi2][e];
    int c = (gi2 >> 3) * 4 + (e >> 2), d = (gi2 & 7) * 4 + (e & 3);
    atomicAdd(&kvb[bh * 1024 + c * 32 + d], sum);
  }
  if (tid < 32){
    float s = ksred[0][tid >> 2][tid & 3] + ksred[1][tid >> 2][tid & 3]
            + ksred[2][tid >> 2][tid & 3] + ksred[3][tid >> 2][tid & 3];
    atomicAdd(&ksb[bh * 32 + tid], s);
  }
}

// ------- out = z*(q@kv) + depthwise5x5(v) + bias, write merged-head bf16 ---
__global__ __launch_bounds__(256) void attn_k(
    const unsigned short* __restrict__ qbuf,
    const unsigned short* __restrict__ vbuf,
    const float* __restrict__ kvb,
    const float* __restrict__ ksb,
    const float* __restrict__ dwc_w,
    const float* __restrict__ dwc_b,
    unsigned short* __restrict__ attn)
{
  int band = blockIdx.x;     // 0..15 (4 feature-map rows each)
  int bh   = blockIdx.y;     // 0..255
  int tid = threadIdx.x, lane = tid & 63, w = tid >> 6;
  __shared__ unsigned short vsm[8][32][64];   // [halo row][channel][x], channel-major
  __shared__ unsigned short outs[256][33];    // z*(q@kv) in bf16, padded
  __shared__ float zs[256];
  __shared__ float ksum_s[32];
  __shared__ float bias_s[32];
  __shared__ float wsm[32][25];
  const unsigned short* qb = qbuf + (size_t)bh * 4096 * 32;
  const unsigned short* vb = vbuf + (size_t)bh * 4096 * 32;
  int y0 = band * 4;

  if (tid < 32){ ksum_s[tid] = ksb[bh * 32 + tid]; bias_s[tid] = dwc_b[tid]; }
  for (int i = tid; i < 800; i += 256) wsm[i / 25][i % 25] = dwc_w[i];
  {
    int xx = tid & 63, dblk = tid >> 6;
    #pragma unroll
    for (int r = 0; r < 8; ++r){
      int y = y0 - 2 + r;
      if (y >= 0 && y < 64){
        u16x8 vv = *(const u16x8*)(vb + ((size_t)y * 64 + xx) * 32 + dblk * 8);
        #pragma unroll
        for (int i = 0; i < 8; ++i) vsm[r][dblk * 8 + i][xx] = vv[i];
      } else {
        #pragma unroll
        for (int i = 0; i < 8; ++i) vsm[r][dblk * 8 + i][xx] = 0;
      }
    }
  }
  __syncthreads();

  {  // z_i = 1/(q_i . ksum + eps)
    int n = band * 256 + tid;
    float zd = 0.f;
    #pragma unroll
    for (int p = 0; p < 4; ++p){
      u16x8 qq = *(const u16x8*)(qb + (size_t)n * 32 + p * 8);
      #pragma unroll
      for (int i = 0; i < 8; ++i) zd += bf2f(qq[i]) * ksum_s[p * 8 + i];
    }
    zs[tid] = 1.f / (zd + 1e-6f);
  }

  // B fragments from kv (32x32): B[k=c][col=d]
  bf16x8 bfr[2];
  #pragma unroll
  for (int nc = 0; nc < 2; ++nc){
    bf16x8 t8;
    #pragma unroll
    for (int j = 0; j < 8; ++j){
      int c = (lane >> 4) * 8 + j;
      int d = nc * 16 + (lane & 15);
      t8[j] = (short)f2bf(kvb[bh * 1024 + c * 32 + d]);
    }
    bfr[nc] = t8;
  }

  f32x4 acc[4][2];
  #pragma unroll
  for (int m = 0; m < 4; ++m){ acc[m][0] = (f32x4){0.f,0.f,0.f,0.f}; acc[m][1] = (f32x4){0.f,0.f,0.f,0.f}; }
  #pragma unroll
  for (int m = 0; m < 4; ++m){
    int row = band * 256 + w * 64 + m * 16 + (lane & 15);
    bf16x8 af = *(const bf16x8*)(qb + (size_t)row * 32 + (lane >> 4) * 8);
    acc[m][0] = __builtin_amdgcn_mfma_f32_16x16x32_bf16(af, bfr[0], acc[m][0], 0, 0, 0);
    acc[m][1] = __builtin_amdgcn_mfma_f32_16x16x32_bf16(af, bfr[1], acc[m][1], 0, 0, 0);
  }
  #pragma unroll
  for (int m = 0; m < 4; ++m)
    #pragma unroll
    for (int nc = 0; nc < 2; ++nc)
      #pragma unroll
      for (int r = 0; r < 4; ++r){
        int tl = w * 64 + m * 16 + (lane >> 4) * 4 + r;  // own-wave rows only
        int d  = nc * 16 + (lane & 15);
        outs[tl][d] = f2bf(acc[m][nc][r] * zs[tl]);
      }

  // conv (thread = one token; all data deps are same-wave or pre-barrier)
  int x = lane;
  int b = bh >> 4, h = bh & 15;
  size_t obase = ((size_t)b * 4096 + band * 256 + tid) * 512 + h * 32;
  #pragma unroll
  for (int d8 = 0; d8 < 4; ++d8){
    u16x8 pack;
    #pragma unroll
    for (int dd = 0; dd < 8; ++dd){
      int d = d8 * 8 + dd;
      float ca = bias_s[d];
      #pragma unroll
      for (int ky = 0; ky < 5; ++ky){
        #pragma unroll
        for (int kx = 0; kx < 5; ++kx){
          int xx = x + kx - 2;
          if (xx >= 0 && xx < 64)
            ca += wsm[d][ky * 5 + kx] * bf2f(vsm[w + ky][d][xx]);
        }
      }
      float val = bf2f(outs[tid][d]) + ca;
      pack[dd] = f2bf(val);
    }
    *(u16x8*)(attn + obase + d8 * 8) = pack;
  }
}

extern "C" void kernel_launch(void* const* d_in, const int* in_sizes, int n_in,
                              void* d_out, int out_size, void* d_ws, size_t ws_size,
                              hipStream_t stream) {
  const float* x       = (const float*)d_in[0];
  const float* Wqkv    = (const float*)d_in[1];
  const float* bqkv    = (const float*)d_in[2];
  const float* pos_enc = (const float*)d_in[3];
  const float* dwc_w   = (const float*)d_in[4];
  const float* dwc_b   = (const float*)d_in[5];
  const float* Wproj   = (const float*)d_in[6];
  const float* bproj   = (const float*)d_in[7];
  float* out = (float*)d_out;
  char* ws = (char*)d_ws;

  // workspace layout (bytes)
  const size_t off_xb    = 0;                       // 67108864
  const size_t off_wqkvt = 67108864;                // 1572864
  const size_t off_wprojt= 68681728;                // 524288
  const size_t off_q     = 69206016;                // 67108864
  const size_t off_k     = 136314880;               // 67108864 (reused as attn)
  const size_t off_v     = 203423744;               // 67108864
  const size_t off_kv    = 270532608;               // 1048576
  const size_t off_ksum  = 271581184;               // 32768
  const size_t needed    = 271613952;
  if (ws_size < needed) return;

  unsigned short* xb     = (unsigned short*)(ws + off_xb);
  unsigned short* wqkvt  = (unsigned short*)(ws + off_wqkvt);
  unsigned short* wprojt = (unsigned short*)(ws + off_wprojt);
  unsigned short* qb     = (unsigned short*)(ws + off_q);
  unsigned short* kb     = (unsigned short*)(ws + off_k);
  unsigned short* vb     = (unsigned short*)(ws + off_v);
  float* kvb = (float*)(ws + off_kv);
  float* ksb = (float*)(ws + off_ksum);
  unsigned short* attn = kb;   // k is dead after kv_k; reuse for merged attn

  convert_x_k<<<16384, 256, 0, stream>>>(x, xb);
  transpose_w_k<<<4096, 256, 0, stream>>>(Wqkv, Wproj, wqkvt, wprojt);
  gemm_k<0><<<6144, 256, 0, stream>>>(xb, wqkvt, bqkv, pos_enc, qb, kb, vb, nullptr, 12);
  (void)hipMemsetAsync(kvb, 0, (size_t)(256 * 1024 + 256 * 32) * sizeof(float), stream);
  kv_k<<<1024, 256, 0, stream>>>(kb, vb, kvb, ksb);
  attn_k<<<dim3(16, 256), 256, 0, stream>>>(qb, vb, kvb, ksb, dwc_w, dwc_b, attn);
  gemm_k<1><<<2048, 256, 0, stream>>>(attn, wprojt, bproj, nullptr, nullptr, nullptr, nullptr, out, 4);
}

// Round 3
// 542.186 us; speedup vs baseline: 1.2339x; 1.2339x over previous
//
#include <hip/hip_runtime.h>
#include <stdint.h>

typedef short bf16x8 __attribute__((ext_vector_type(8)));
typedef float f32x4 __attribute__((ext_vector_type(4)));
typedef unsigned short u16x8 __attribute__((ext_vector_type(8)));

__device__ __forceinline__ unsigned short f2bf(float f){
  uint32_t u = __builtin_bit_cast(uint32_t, f);
  u += 0x7FFFu + ((u >> 16) & 1u);
  return (unsigned short)(u >> 16);
}
__device__ __forceinline__ float bf2f(unsigned short h){
  uint32_t u = ((uint32_t)h) << 16;
  return __builtin_bit_cast(float, u);
}
__device__ __forceinline__ float bflo(uint32_t dw){      // low u16 as bf16
  return __builtin_bit_cast(float, dw << 16);
}
__device__ __forceinline__ float bfhi(uint32_t dw){      // high u16 as bf16
  return __builtin_bit_cast(float, dw & 0xffff0000u);
}

__device__ __forceinline__ void gload_lds16(const void* g, void* l){
  __builtin_amdgcn_global_load_lds(
      (const __attribute__((address_space(1))) uint32_t*)(g),
      (__attribute__((address_space(3))) uint32_t*)(l),
      16, 0, 0);
}

// ---------------- convert x (fp32 -> bf16), 8 elems/thread ----------------
__global__ __launch_bounds__(256) void convert_x_k(const float* __restrict__ x,
                                                   unsigned short* __restrict__ xb){
  size_t i = (size_t)blockIdx.x * 256 + threadIdx.x;
  const float4* p = (const float4*)x + i * 2;
  float4 a = p[0], b = p[1];
  u16x8 o;
  o[0] = f2bf(a.x); o[1] = f2bf(a.y); o[2] = f2bf(a.z); o[3] = f2bf(a.w);
  o[4] = f2bf(b.x); o[5] = f2bf(b.y); o[6] = f2bf(b.z); o[7] = f2bf(b.w);
  *(u16x8*)(xb + i * 8) = o;
}

// ---------------- transpose + convert weights -----------------------------
__global__ __launch_bounds__(256) void transpose_w_k(const float* __restrict__ Wqkv,
                                                     const float* __restrict__ Wproj,
                                                     unsigned short* __restrict__ Wqkvt,
                                                     unsigned short* __restrict__ Wprojt){
  int i = blockIdx.x * 256 + threadIdx.x;
  if (i < 786432){
    int j = i >> 9, c = i & 511;
    Wqkvt[i] = f2bf(Wqkv[(size_t)c * 1536 + j]);
  } else {
    int e = i - 786432;
    int j = e >> 9, c = e & 511;
    Wprojt[e] = f2bf(Wproj[(size_t)c * 512 + j]);
  }
}

// ---------------- GEMM: C = A(Mx512) * Bt(Nx512)^T, bf16 MFMA --------------
template<int EPI>
__global__ __launch_bounds__(256, 2) void gemm_k(
    const unsigned short* __restrict__ A,
    const unsigned short* __restrict__ Bt,
    const float* __restrict__ bias,
    const float* __restrict__ pos_enc,
    unsigned short* __restrict__ oq,
    unsigned short* __restrict__ ok,
    unsigned short* __restrict__ ov,
    float* __restrict__ op,
    int NTN)
{
  __shared__ unsigned short As[128 * 64];
  __shared__ unsigned short Bs[128 * 64];
  int tid = threadIdx.x, lane = tid & 63, wid = tid >> 6;
  int nwg = gridDim.x;
  int b0 = blockIdx.x;
  int cpx = nwg >> 3;
  int swz = (b0 & 7) * cpx + (b0 >> 3);      // XCD-aware swizzle (nwg % 8 == 0)
  int tm = swz / NTN, tn = swz - tm * NTN;
  int row0 = tm << 7, col0 = tn << 7;
  int wr = wid >> 1, wc = wid & 1;

  f32x4 acc[4][4];
  #pragma unroll
  for (int m = 0; m < 4; ++m)
    #pragma unroll
    for (int n = 0; n < 4; ++n)
      acc[m][n] = (f32x4){0.f, 0.f, 0.f, 0.f};

  int sr = lane >> 3;
  int sc = (lane & 7) * 8;

  for (int kt = 0; kt < 8; ++kt){
    int k0 = kt * 64;
    #pragma unroll
    for (int it = 0; it < 4; ++it){
      int chunk = wid * 4 + it;
      int r = chunk * 8 + sr;
      gload_lds16(A  + (size_t)(row0 + r) * 512 + k0 + sc, &As[chunk * 512]);
      gload_lds16(Bt + (size_t)(col0 + r) * 512 + k0 + sc, &Bs[chunk * 512]);
    }
    __syncthreads();
    #pragma unroll
    for (int kk = 0; kk < 2; ++kk){
      bf16x8 af[4], bfr[4];
      int kidx = kk * 32 + (lane >> 4) * 8;
      #pragma unroll
      for (int m = 0; m < 4; ++m)
        af[m] = *(const bf16x8*)&As[(wr * 64 + m * 16 + (lane & 15)) * 64 + kidx];
      #pragma unroll
      for (int n = 0; n < 4; ++n)
        bfr[n] = *(const bf16x8*)&Bs[(wc * 64 + n * 16 + (lane & 15)) * 64 + kidx];
      #pragma unroll
      for (int m = 0; m < 4; ++m)
        #pragma unroll
        for (int n = 0; n < 4; ++n)
          acc[m][n] = __builtin_amdgcn_mfma_f32_16x16x32_bf16(af[m], bfr[n], acc[m][n], 0, 0, 0);
    }
    __syncthreads();
  }

  #pragma unroll
  for (int m = 0; m < 4; ++m){
    #pragma unroll
    for (int n = 0; n < 4; ++n){
      #pragma unroll
      for (int r = 0; r < 4; ++r){
        int rrow = row0 + wr * 64 + m * 16 + (lane >> 4) * 4 + r;
        int ccol = col0 + wc * 64 + n * 16 + (lane & 15);
        float val = acc[m][n][r] + bias[ccol];
        if constexpr (EPI == 0){
          int part = ccol >> 9;
          int cc = ccol & 511;
          int bb = rrow >> 12, nn = rrow & 4095;
          int h = cc >> 5, d = cc & 31;
          size_t dst = ((size_t)((bb << 4) + h) * 4096 + nn) * 32 + d;
          if (part == 0){
            oq[dst] = f2bf(fmaxf(val, 0.f));
          } else if (part == 1){
            val += pos_enc[(size_t)nn * 512 + cc];
            ok[dst] = f2bf(fmaxf(val, 0.f));
          } else {
            ov[dst] = f2bf(val);
          }
        } else {
          op[(size_t)rrow * 512 + ccol] = val;
        }
      }
    }
  }
}

// ---------------- kv = k^T v (32x32) + ksum, per head, 4-way n-split ------
__global__ __launch_bounds__(256) void kv_k(const unsigned short* __restrict__ kbuf,
                                            const unsigned short* __restrict__ vbuf,
                                            float* __restrict__ kvb,
                                            float* __restrict__ ksb){
  int bh  = blockIdx.x >> 2;
  int seg = blockIdx.x & 3;
  __shared__ float ks[64][36];
  __shared__ float vs[64][36];
  __shared__ float red[4][64][16];
  __shared__ float ksred[4][8][4];
  int tid = threadIdx.x;
  int g = tid >> 6, gi = tid & 63;
  int c0 = (gi >> 3) * 4, d0 = (gi & 7) * 4;
  float acc[4][4] = {};
  float ksacc[4] = {0.f, 0.f, 0.f, 0.f};
  const unsigned short* kb = kbuf + (size_t)bh * 4096 * 32 + (size_t)seg * 1024 * 32;
  const unsigned short* vb = vbuf + (size_t)bh * 4096 * 32 + (size_t)seg * 1024 * 32;
  int er = tid >> 2;
  int ec = (tid & 3) * 8;
  for (int t = 0; t < 16; ++t){
    __syncthreads();
    u16x8 kk8 = *(const u16x8*)(kb + ((size_t)t * 64 + er) * 32 + ec);
    u16x8 vv8 = *(const u16x8*)(vb + ((size_t)t * 64 + er) * 32 + ec);
    #pragma unroll
    for (int i = 0; i < 8; ++i){ ks[er][ec + i] = bf2f(kk8[i]); vs[er][ec + i] = bf2f(vv8[i]); }
    __syncthreads();
    for (int nn = g; nn < 64; nn += 4){
      f32x4 k4 = *(const f32x4*)&ks[nn][c0];
      f32x4 v4 = *(const f32x4*)&vs[nn][d0];
      #pragma unroll
      for (int i = 0; i < 4; ++i)
        #pragma unroll
        for (int j = 0; j < 4; ++j)
          acc[i][j] += k4[i] * v4[j];
      if ((gi & 7) == 0){
        #pragma unroll
        for (int i = 0; i < 4; ++i) ksacc[i] += k4[i];
      }
    }
  }
  __syncthreads();
  #pragma unroll
  for (int i = 0; i < 4; ++i)
    #pragma unroll
    for (int j = 0; j < 4; ++j)
      red[g][gi][i * 4 + j] = acc[i][j];
  if ((gi & 7) == 0){
    #pragma unroll
    for (int i = 0; i < 4; ++i) ksred[g][gi >> 3][i] = ksacc[i];
  }
  __syncthreads();
  for (int s = tid; s < 1024; s += 256){
    int gi2 = s >> 4, e = s & 15;
    float sum = red[0][gi2][e] + red[1][gi2][e] + red[2][gi2][e] + red[3][gi2][e];
    int c = (gi2 >> 3) * 4 + (e >> 2), d = (gi2 & 7) * 4 + (e & 3);
    atomicAdd(&kvb[bh * 1024 + c * 32 + d], sum);
  }
  if (tid < 32){
    float s = ksred[0][tid >> 2][tid & 3] + ksred[1][tid >> 2][tid & 3]
            + ksred[2][tid >> 2][tid & 3] + ksred[3][tid >> 2][tid & 3];
    atomicAdd(&ksb[bh * 32 + tid], s);
  }
}

// ------- out = z*(q@kv) + depthwise5x5(v) + bias, register sliding conv ----
// block = (band of 16 fm rows, bh); wave = x-row, owns 8 channels (4 pairs)
__global__ __launch_bounds__(256, 2) void attn_k2(
    const unsigned short* __restrict__ qbuf,
    const unsigned short* __restrict__ vbuf,
    const float* __restrict__ kvb,
    const float* __restrict__ ksb,
    const float* __restrict__ dwc_w,
    const float* __restrict__ dwc_b,
    unsigned short* __restrict__ attn)
{
  int band = blockIdx.x;          // 0..3 (16 rows each)
  int bh   = blockIdx.y;          // 0..255
  int tid = threadIdx.x, lane = tid & 63, w = tid >> 6;
  __shared__ unsigned short outs[1024][36];   // z*(q@kv) bf16, 72B row stride
  __shared__ float zs[1024];
  __shared__ float ksum_s[32];

  const unsigned short* qb = qbuf + (size_t)bh * 4096 * 32 + (size_t)band * 1024 * 32;
  const unsigned short* vb = vbuf + (size_t)bh * 4096 * 32;

  if (tid < 32) ksum_s[tid] = ksb[bh * 32 + tid];
  __syncthreads();

  // ---- z for the block's 1024 tokens ----
  for (int p = 0; p < 4; ++p){
    int t = p * 256 + tid;
    float zd = 0.f;
    #pragma unroll
    for (int pp = 0; pp < 4; ++pp){
      u16x8 qq = *(const u16x8*)(qb + (size_t)t * 32 + pp * 8);
      #pragma unroll
      for (int i = 0; i < 8; ++i) zd += bf2f(qq[i]) * ksum_s[pp * 8 + i];
    }
    zs[t] = 1.f / (zd + 1e-6f);
  }

  // ---- kv B-fragments ----
  bf16x8 bfr[2];
  #pragma unroll
  for (int nc = 0; nc < 2; ++nc){
    bf16x8 t8;
    #pragma unroll
    for (int j = 0; j < 8; ++j){
      int c = (lane >> 4) * 8 + j;
      int d = nc * 16 + (lane & 15);
      t8[j] = (short)f2bf(kvb[bh * 1024 + c * 32 + d]);
    }
    bfr[nc] = t8;
  }
  __syncthreads();   // zs ready

  // ---- attn passes: z*(q@kv) -> outs ----
  for (int p = 0; p < 4; ++p){
    f32x4 acc[4][2];
    #pragma unroll
    for (int m = 0; m < 4; ++m){ acc[m][0] = (f32x4){0.f,0.f,0.f,0.f}; acc[m][1] = (f32x4){0.f,0.f,0.f,0.f}; }
    #pragma unroll
    for (int m = 0; m < 4; ++m){
      int row = p * 256 + w * 64 + m * 16 + (lane & 15);
      bf16x8 af = *(const bf16x8*)(qb + (size_t)row * 32 + (lane >> 4) * 8);
      acc[m][0] = __builtin_amdgcn_mfma_f32_16x16x32_bf16(af, bfr[0], acc[m][0], 0, 0, 0);
      acc[m][1] = __builtin_amdgcn_mfma_f32_16x16x32_bf16(af, bfr[1], acc[m][1], 0, 0, 0);
    }
    #pragma unroll
    for (int m = 0; m < 4; ++m)
      #pragma unroll
      for (int nc = 0; nc < 2; ++nc)
        #pragma unroll
        for (int r = 0; r < 4; ++r){
          int lrow = p * 256 + w * 64 + m * 16 + (lane >> 4) * 4 + r;
          int col = nc * 16 + (lane & 15);
          outs[lrow][col] = f2bf(acc[m][nc][r] * zs[lrow]);
        }
  }
  __syncthreads();   // outs ready

  // ---- depthwise 5x5 conv, register sliding window, + merge + store ----
  int du = __builtin_amdgcn_readfirstlane(w);
  int x = lane;
  int b = bh >> 4, h = bh & 15;
  int y0 = band * 16;
  int xm2 = lane - 2, xm1 = lane - 1, xp1 = lane + 1, xp2 = lane + 2;

  for (int pair = 0; pair < 4; ++pair){
    int dbase = du * 8 + pair * 2;
    float w0[25], w1[25];
    #pragma unroll
    for (int j = 0; j < 25; ++j){
      w0[j] = dwc_w[dbase * 25 + j];
      w1[j] = dwc_w[(dbase + 1) * 25 + j];
    }
    float cb0 = dwc_b[dbase], cb1 = dwc_b[dbase + 1];

    uint32_t rowd[20];
    #pragma unroll
    for (int il = 0; il < 20; ++il){
      int yi = y0 - 2 + il;
      rowd[il] = (yi >= 0 && yi < 64)
        ? *(const uint32_t*)(vb + ((size_t)yi * 64 + x) * 32 + dbase) : 0u;
    }

    float a0[5], a1[5];
    #pragma unroll
    for (int il = 0; il < 20; ++il){
      uint32_t d0 = rowd[il];
      uint32_t dm2 = (uint32_t)__shfl((int)d0, xm2); if (lane < 2)  dm2 = 0;
      uint32_t dm1 = (uint32_t)__shfl((int)d0, xm1); if (lane < 1)  dm1 = 0;
      uint32_t dp1 = (uint32_t)__shfl((int)d0, xp1); if (lane > 62) dp1 = 0;
      uint32_t dp2 = (uint32_t)__shfl((int)d0, xp2); if (lane > 61) dp2 = 0;
      float f0[5], f1[5];
      f0[0] = bflo(dm2); f1[0] = bfhi(dm2);
      f0[1] = bflo(dm1); f1[1] = bfhi(dm1);
      f0[2] = bflo(d0);  f1[2] = bfhi(d0);
      f0[3] = bflo(dp1); f1[3] = bfhi(dp1);
      f0[4] = bflo(dp2); f1[4] = bfhi(dp2);
      #pragma unroll
      for (int ky = 0; ky < 5; ++ky){
        int ol = il - ky;
        if (ol < 0 || ol > 15) continue;
        int s = ol % 5;     // compile-time after unroll
        if (ky == 0){
          a0[s] = w0[0] * f0[0];
          a1[s] = w1[0] * f1[0];
          #pragma unroll
          for (int kx = 1; kx < 5; ++kx){
            a0[s] += w0[kx] * f0[kx];
            a1[s] += w1[kx] * f1[kx];
          }
        } else {
          #pragma unroll
          for (int kx = 0; kx < 5; ++kx){
            a0[s] += w0[ky * 5 + kx] * f0[kx];
            a1[s] += w1[ky * 5 + kx] * f1[kx];
          }
        }
      }
      // emit completed output row ol = il - 4
      if (il >= 4){
        int ol = il - 4;
        int s = ol % 5;
        int ltok = ol * 64 + x;
        uint32_t ov = *(const uint32_t*)&outs[ltok][dbase];
        float o0 = bflo(ov) + a0[s] + cb0;
        float o1 = bfhi(ov) + a1[s] + cb1;
        uint32_t pk = ((uint32_t)f2bf(o1) << 16) | (uint32_t)f2bf(o0);
        size_t gaddr = ((size_t)b * 4096 + band * 1024 + ltok) * 512 + h * 32 + dbase;
        *(uint32_t*)(attn + gaddr) = pk;
      }
    }
  }
}

extern "C" void kernel_launch(void* const* d_in, const int* in_sizes, int n_in,
                              void* d_out, int out_size, void* d_ws, size_t ws_size,
                              hipStream_t stream) {
  const float* x       = (const float*)d_in[0];
  const float* Wqkv    = (const float*)d_in[1];
  const float* bqkv    = (const float*)d_in[2];
  const float* pos_enc = (const float*)d_in[3];
  const float* dwc_w   = (const float*)d_in[4];
  const float* dwc_b   = (const float*)d_in[5];
  const float* Wproj   = (const float*)d_in[6];
  const float* bproj   = (const float*)d_in[7];
  float* out = (float*)d_out;
  char* ws = (char*)d_ws;

  const size_t off_xb    = 0;
  const size_t off_wqkvt = 67108864;
  const size_t off_wprojt= 68681728;
  const size_t off_q     = 69206016;
  const size_t off_k     = 136314880;
  const size_t off_v     = 203423744;
  const size_t off_kv    = 270532608;
  const size_t off_ksum  = 271581184;
  const size_t needed    = 271613952;
  if (ws_size < needed) return;

  unsigned short* xb     = (unsigned short*)(ws + off_xb);
  unsigned short* wqkvt  = (unsigned short*)(ws + off_wqkvt);
  unsigned short* wprojt = (unsigned short*)(ws + off_wprojt);
  unsigned short* qb     = (unsigned short*)(ws + off_q);
  unsigned short* kb     = (unsigned short*)(ws + off_k);
  unsigned short* vb     = (unsigned short*)(ws + off_v);
  float* kvb = (float*)(ws + off_kv);
  float* ksb = (float*)(ws + off_ksum);
  unsigned short* attn = kb;   // k dead after kv_k; reuse for merged attn

  convert_x_k<<<16384, 256, 0, stream>>>(x, xb);
  transpose_w_k<<<4096, 256, 0, stream>>>(Wqkv, Wproj, wqkvt, wprojt);
  gemm_k<0><<<6144, 256, 0, stream>>>(xb, wqkvt, bqkv, pos_enc, qb, kb, vb, nullptr, 12);
  (void)hipMemsetAsync(kvb, 0, (size_t)(256 * 1024 + 256 * 32) * sizeof(float), stream);
  kv_k<<<1024, 256, 0, stream>>>(kb, vb, kvb, ksb);
  attn_k2<<<dim3(4, 256), 256, 0, stream>>>(qb, vb, kvb, ksb, dwc_w, dwc_b, attn);
  gemm_k<1><<<2048, 256, 0, stream>>>(attn, wprojt, bproj, nullptr, nullptr, nullptr, nullptr, out, 4);
}